// Round 7
// baseline (1255.226 us; speedup 1.0000x reference)
//
#include <hip/hip_runtime.h>
#include <stdint.h>
#include <math.h>

typedef unsigned int u32;
typedef unsigned long long u64;

#define E_CNT   8192
#define N_CNT   4096
#define TOT_N   67108864u      // E*E = 2^26
#define OUT_K   16384          // K*E
#define NBW     128            // bitmap words per node row
#define MAGIC   0x5EEDC0DEu

// ---- workspace word-offsets (u32 index into ws) ----
#define W_BAD      0           // u32[524288]  2 MiB bad bitmap
#define W_CNT_DST  524288      // u32[4096]
#define W_CNT_SRC  528384      // u32[4096]
#define W_CCOUNT   532480      // u32[1024]
#define W_SCAL     533504      // u32[64]: [0]=neg_sum [1]=hist_done [2]=terms_done [3]=T9 [4]=magic
#define ZERO_WORDS 533568      // contiguous init region [0, ZERO_WORDS)
#define S_NEG 0
#define S_HIST 1
#define S_TD 2
#define S_T9 3
#define S_MG 4
#define OFF_KEEPBM 0x210000    // bytes; u64[1<<20] 8 MiB (fully overwritten each call)

// rotl as a single v_alignbit_b32
__device__ __forceinline__ u32 rotl32(u32 x, u32 d) {
  return __builtin_amdgcn_alignbit(x, x, 32u - d);
}

// Two interleaved JAX threefry2x32 evals, key=(0,42), counters (0,ia),(0,ib).
// Returns bits = o0 ^ o1 (partitionable draw). Bit-exact verified R2-R6 (absmax 0).
__device__ __forceinline__ void threefry2_0_42(u32 ia, u32 ib, u32& bits_a, u32& bits_b) {
  const u32 k1 = 42u, k2 = 0x1BD11BF0u; // 0 ^ 42 ^ 0x1BD11BDA
  u32 A0 = 0u, A1 = ia + k1;
  u32 B0 = 0u, B1 = ib + k1;
#define R2(r) { A0 += A1; B0 += B1; A1 = rotl32(A1, r); B1 = rotl32(B1, r); A1 ^= A0; B1 ^= B0; }
  R2(13) R2(15) R2(26) R2(6)
  A0 += k1; B0 += k1; A1 += k2 + 1u; B1 += k2 + 1u;
  R2(17) R2(29) R2(16) R2(24)
  A0 += k2; B0 += k2; A1 += 2u; B1 += 2u;
  R2(13) R2(15) R2(26) R2(6)
  A1 += k1 + 3u; B1 += k1 + 3u;
  R2(17) R2(29) R2(16) R2(24)
  A0 += k1; B0 += k1; A1 += k2 + 4u; B1 += k2 + 4u;
  R2(13) R2(15) R2(26) R2(6)
  A0 += k2; B0 += k2; A1 += 5u; B1 += 5u;
#undef R2
  bits_a = A0 ^ A1;
  bits_b = B0 ^ B1;
}

// --- D1: bitmap init (zero + self-bit fused, plain stores), zero cnt/ccount/scal, prefill out ---
__global__ void k_init(const int* __restrict__ src, const int* __restrict__ dst,
                       u32* __restrict__ ws32, int* __restrict__ out) {
  u32 g = blockIdx.x * 256u + threadIdx.x;
  if (g < 524288u) {
    u32 row = g >> 7, cw = g & 127u;          // word cw of node row's 128-word bitmap
    ws32[g] = (cw == (row >> 5)) ? (1u << (row & 31u)) : 0u;   // self-bit {n}
  } else if (g < ZERO_WORDS) {
    ws32[g] = 0u;                             // cnt_dst, cnt_src, ccount, scalars
  } else {
    u32 r = g - ZERO_WORDS;
    if (r < OUT_K) {                          // nonzero fill_value=0 -> (src[0], dst[0])
      out[r] = src[0];
      out[OUT_K + r] = dst[0];
    }
  }
}

// --- D2: fused pre (8 opener blocks) + threefry sample (all 32768 blocks) ---
__global__ void __launch_bounds__(256, 8) k_main(const int* __restrict__ src,
                                                 const int* __restrict__ dst,
                                                 u32* __restrict__ ws32,
                                                 u64* __restrict__ keep_bm) {
  u32* bad     = ws32 + W_BAD;
  u32* cnt_dst = ws32 + W_CNT_DST;
  u32* cnt_src = ws32 + W_CNT_SRC;
  u32* ccount  = ws32 + W_CCOUNT;
  u32* scal    = ws32 + W_SCAL;
  const u32 b = blockIdx.x, t = threadIdx.x;
  const u32 wv = t >> 6, ln = t & 63u;
  __shared__ u32 red[4];
  __shared__ u32 sh_t9;

  // ---- stage A: openers (blocks 0..7; dispatched first -> resident) ----
  if (b < 8u) {
    // histograms for edge slice [b*1024, +1024)
#pragma unroll
    for (int j = 0; j < 4; ++j) {
      u32 e = b * 1024u + (u32)j * 256u + t;
      atomicAdd(&cnt_dst[(u32)dst[e]], 1u);
      atomicAdd(&cnt_src[(u32)src[e]], 1u);
    }
    __threadfence();
    __syncthreads();
    if (t == 0) {
      atomicAdd(&scal[S_HIST], 1u);           // arrive
      while (__hip_atomic_load(&scal[S_HIST], __ATOMIC_ACQUIRE,
                               __HIP_MEMORY_SCOPE_AGENT) < 8u)
        __builtin_amdgcn_s_sleep(8);          // plain-load poll (no RMW ping-pong)
      __threadfence();
    }
    __syncthreads();
    // edge insert + dedup'd terms: num_neg = E^2 - sum(cnt_src[s]*cnt_dst[d] over badset pairs)
    u32 acc = 0;
#pragma unroll
    for (int j = 0; j < 4; ++j) {
      u32 e = b * 1024u + (u32)j * 256u + t;
      u32 s = (u32)src[e], d = (u32)dst[e];
      u32 bit = 1u << (d & 31u);
      u32 old = atomicOr(&bad[s * NBW + (d >> 5)], bit);
      if (!(old & bit)) acc += cnt_src[s] * cnt_dst[d];   // newly-set: exactly-once
    }
#pragma unroll
    for (int j = 0; j < 2; ++j) {             // self terms {n}: cnt_src[n]*cnt_dst[n]
      u32 n = b * 512u + (u32)j * 256u + t;
      acc += cnt_src[n] * cnt_dst[n];
    }
#pragma unroll
    for (int off = 32; off > 0; off >>= 1) acc += __shfl_down(acc, off, 64);
    if (ln == 0) red[wv] = acc;
    __syncthreads();
    if (t == 0) {
      atomicAdd(&scal[S_NEG], red[0] + red[1] + red[2] + red[3]);
      __threadfence();
      if (atomicAdd(&scal[S_TD], 1u) == 7u) { // last opener: publish threshold
        u32 sum = atomicAdd(&scal[S_NEG], 0u);
        u32 nn = TOT_N - sum;                 // num_negatives
        u32 ratio = nn >> 13;                 // // E
        float kp = 2.0f / (float)ratio;       // f32(K)/f32(ratio), as JAX
        u32 T = (u32)ceil((double)kp * 8388608.0);   // u<kp <=> (bits>>9) < T
        u32 T9 = (T >= (1u << 23)) ? 0xFFFFFFFFu : (T << 9);
        atomicExch(&scal[S_T9], T9);
        __threadfence();
        atomicExch(&scal[S_MG], MAGIC);
      }
    }
  }

  // ---- stage B: threefry own 2048-elem slice FIRST (hides opener latency) ----
  const u32 i0w = b * 2048u + wv * 512u;      // wave covers 512 consecutive i
  u32 bits[8];
#pragma unroll
  for (int j = 0; j < 4; ++j) {
    u32 ia = i0w + (u32)j * 128u + ln;
    threefry2_0_42(ia, ia + 64u, bits[2 * j], bits[2 * j + 1]);
  }

  // ---- stage C: gate (by now openers are long done; ~zero spin) ----
  if (t == 0) {
    while (__hip_atomic_load(&scal[S_MG], __ATOMIC_ACQUIRE,
                             __HIP_MEMORY_SCOPE_AGENT) != MAGIC)
      __builtin_amdgcn_s_sleep(16);
    __threadfence();
    sh_t9 = __hip_atomic_load(&scal[S_T9], __ATOMIC_RELAXED, __HIP_MEMORY_SCOPE_AGENT);
  }
  __syncthreads();
  const u32 T9 = sh_t9;

  // ---- stage D: ballots + rare bad-bitmap refine + stores ----
  u64 words[8]; u64 any = 0;
#pragma unroll
  for (int k = 0; k < 8; ++k) { words[k] = __ballot(bits[k] < T9); any |= words[k]; }
  if (any) {
#pragma unroll
    for (int k = 0; k < 8; ++k) {
      if (words[k]) {
        u32 i = i0w + (u32)k * 64u + ln;
        bool kp2 = (words[k] >> ln) & 1ull;
        if (kp2) {
          u32 n = (u32)src[i >> 13], v = (u32)dst[i & 8191u];
          kp2 = ((bad[n * NBW + (v >> 5)] >> (v & 31u)) & 1u) == 0u;
        }
        words[k] = __ballot(kp2);
      }
    }
  }
  if (ln == 0) {
    ulonglong2* p = (ulonglong2*)&keep_bm[i0w >> 6];   // 64B aligned
    p[0] = make_ulonglong2(words[0], words[1]);
    p[1] = make_ulonglong2(words[2], words[3]);
    p[2] = make_ulonglong2(words[4], words[5]);
    p[3] = make_ulonglong2(words[6], words[7]);
    u32 c = 0;
#pragma unroll
    for (int k = 0; k < 8; ++k) c += (u32)__popcll(words[k]);
    if (c) atomicAdd(&ccount[i0w >> 16], c);
  }
}

// 64-lane inclusive scan via shfl (no barriers)
__device__ __forceinline__ u32 wave_iscan(u32 v, u32 ln) {
#pragma unroll
  for (int off = 1; off < 64; off <<= 1) {
    u32 n = __shfl_up(v, off, 64);
    if (ln >= (u32)off) v += n;
  }
  return v;
}

// --- D3: ordered compaction; inline scan of 1024 chunk counts ---
__global__ void k_compact(const int* __restrict__ src, const int* __restrict__ dst,
                          const u64* __restrict__ keep_bm, const u32* __restrict__ ccount,
                          int* __restrict__ out) {
  const u32 c = blockIdx.x, t = threadIdx.x;   // chunk c; 256 threads
  const u32 wv = t >> 6, ln = t & 63u;
  __shared__ u32 wtot[4], wtot2[4];
  __shared__ u32 base_sh;

  // exclusive prefix of ccount[0..c-1] (each thread holds 4 counts)
  u32 v0 = ccount[4 * t], v1 = ccount[4 * t + 1], v2 = ccount[4 * t + 2], v3 = ccount[4 * t + 3];
  u32 s4 = v0 + v1 + v2 + v3;
  u32 is = wave_iscan(s4, ln);
  if (ln == 63) wtot[wv] = is;
  __syncthreads();
  u32 wpre = 0;
#pragma unroll
  for (int w = 0; w < 4; ++w) if ((u32)w < wv) wpre += wtot[w];
  if (t == (c >> 2)) {
    u32 excl = (is + wpre) - s4;
    if ((c & 3u) > 0) excl += v0;
    if ((c & 3u) > 1) excl += v1;
    if ((c & 3u) > 2) excl += v2;
    base_sh = excl;
  }
  __syncthreads();
  u32 rank0 = base_sh;

  // compact own chunk: 1024 u64 words, 4/thread, in order
  const u64* wp = keep_bm + (size_t)c * 1024u;
  u64 w[4]; u32 cnt = 0;
#pragma unroll
  for (int k = 0; k < 4; ++k) { w[k] = wp[4 * t + k]; cnt += (u32)__popcll(w[k]); }
  u32 is2 = wave_iscan(cnt, ln);
  if (ln == 63) wtot2[wv] = is2;
  __syncthreads();
  u32 wpre2 = 0;
#pragma unroll
  for (int ww = 0; ww < 4; ++ww) if ((u32)ww < wv) wpre2 += wtot2[ww];
  u32 rank = rank0 + (is2 + wpre2) - cnt;      // global rank of my first set bit
  u32 tb = (c << 16) + (t << 8);               // 4 u64 = 256 elems per thread
#pragma unroll
  for (int k = 0; k < 4; ++k) {
    u64 bits = w[k];
    while (bits) {
      int bb = __ffsll((unsigned long long)bits) - 1;
      if (rank < OUT_K) {
        u32 tt = tb + (u32)k * 64u + (u32)bb;
        out[rank]         = src[tt >> 13];     // edge_src[rows]
        out[OUT_K + rank] = dst[tt & 8191u];   // edge_dst[cols]
      }
      rank++;
      bits &= bits - 1;
    }
  }
}

extern "C" void kernel_launch(void* const* d_in, const int* in_sizes, int n_in,
                              void* d_out, int out_size, void* d_ws, size_t ws_size,
                              hipStream_t stream) {
  const int* src = (const int*)d_in[1];  // edge_src
  const int* dst = (const int*)d_in[2];  // edge_dst  (node_feature d_in[0] unused)
  int* out = (int*)d_out;                // [edge_src_neg(16384) | edge_dst_neg(16384)]
  u32* ws32 = (u32*)d_ws;
  u64* keep_bm = (u64*)((char*)d_ws + OFF_KEEPBM);
  u32* ccount = ws32 + W_CCOUNT;

  k_init<<<2149, 256, 0, stream>>>(src, dst, ws32, out);                 // zero+self+prefill
  k_main<<<TOT_N / 2048, 256, 0, stream>>>(src, dst, ws32, keep_bm);     // pre + sample
  k_compact<<<1024, 256, 0, stream>>>(src, dst, keep_bm, ccount, out);   // ordered emit
}

// Round 8
// 193.497 us; speedup vs baseline: 6.4870x; 6.4870x over previous
//
#include <hip/hip_runtime.h>
#include <stdint.h>
#include <math.h>

typedef unsigned int u32;
typedef unsigned long long u64;

#define E_CNT   8192
#define N_CNT   4096
#define TOT_N   67108864u      // E*E = 2^26
#define OUT_K   16384          // K*E
#define NBW     128            // bitmap words per node row

// ---- workspace word-offsets (u32 index into ws) ----
#define W_BAD      0           // u32[524288]  2 MiB bad bitmap
#define W_CNT_DST  524288      // u32[4096]
#define W_CNT_SRC  528384      // u32[4096]
#define W_CCOUNT   532480      // u32[1024]
#define W_SCAL     533504      // u32[8]: [0]=neg_acc [1]=ticket [2]=T9
#define S_NEG 0
#define S_TD  1
#define S_T9  2
#define OFF_KEEPBM 0x210000    // bytes; u64[1<<20] 8 MiB (fully overwritten)

// rotl as a single v_alignbit_b32
__device__ __forceinline__ u32 rotl32(u32 x, u32 d) {
  return __builtin_amdgcn_alignbit(x, x, 32u - d);
}

// Four interleaved JAX threefry2x32 evals, key=(0,42), counters (0,i0..i3).
// Returns bits = o0 ^ o1 per element (partitionable draw). Bit-exact (R2-R7: absmax 0).
__device__ __forceinline__ void threefry4_0_42(u32 i0, u32 i1, u32 i2, u32 i3, u32 o[4]) {
  const u32 k1 = 42u, k2 = 0x1BD11BF0u;   // 0 ^ 42 ^ 0x1BD11BDA
  u32 A0 = 0u, A1 = i0 + k1;
  u32 B0 = 0u, B1 = i1 + k1;
  u32 C0 = 0u, C1 = i2 + k1;
  u32 D0 = 0u, D1 = i3 + k1;
#define R4(r) { A0 += A1; B0 += B1; C0 += C1; D0 += D1; \
                A1 = rotl32(A1, r); B1 = rotl32(B1, r); C1 = rotl32(C1, r); D1 = rotl32(D1, r); \
                A1 ^= A0; B1 ^= B0; C1 ^= C0; D1 ^= D0; }
  R4(13) R4(15) R4(26) R4(6)
  A0 += k1; B0 += k1; C0 += k1; D0 += k1;
  A1 += k2 + 1u; B1 += k2 + 1u; C1 += k2 + 1u; D1 += k2 + 1u;
  R4(17) R4(29) R4(16) R4(24)
  A0 += k2; B0 += k2; C0 += k2; D0 += k2;
  A1 += 2u; B1 += 2u; C1 += 2u; D1 += 2u;
  R4(13) R4(15) R4(26) R4(6)
  A1 += k1 + 3u; B1 += k1 + 3u; C1 += k1 + 3u; D1 += k1 + 3u;
  R4(17) R4(29) R4(16) R4(24)
  A0 += k1; B0 += k1; C0 += k1; D0 += k1;
  A1 += k2 + 4u; B1 += k2 + 4u; C1 += k2 + 4u; D1 += k2 + 4u;
  R4(13) R4(15) R4(26) R4(6)
  A0 += k2; B0 += k2; C0 += k2; D0 += k2;
  A1 += 5u; B1 += 5u; C1 += 5u; D1 += 5u;
#undef R4
  o[0] = A0 ^ A1; o[1] = B0 ^ B1; o[2] = C0 ^ C1; o[3] = D0 ^ D1;
}

// --- D1: init. Block 0: LDS histograms -> global cnt arrays. Others: pattern init. ---
__global__ void k_init(const int* __restrict__ src, const int* __restrict__ dst,
                       u32* __restrict__ ws32, int* __restrict__ out) {
  const u32 b = blockIdx.x, t = threadIdx.x;
  if (b == 0) {                              // histograms, block-local (no cross-block hazard)
    __shared__ u32 hs[N_CNT], hd[N_CNT];
#pragma unroll
    for (int k = 0; k < 16; ++k) { hs[t + 256 * k] = 0; hd[t + 256 * k] = 0; }
    __syncthreads();
#pragma unroll
    for (int k = 0; k < 32; ++k) {
      u32 e = t + 256u * (u32)k;
      atomicAdd(&hs[(u32)src[e]], 1u);
      atomicAdd(&hd[(u32)dst[e]], 1u);
    }
    __syncthreads();
#pragma unroll
    for (int k = 0; k < 16; ++k) {
      u32 n = t + 256 * k;
      ws32[W_CNT_SRC + n] = hs[n];
      ws32[W_CNT_DST + n] = hd[n];
    }
    if (t < 8) ws32[W_SCAL + t] = 0;
    return;
  }
  if (b == 1 && t < 8) ws32[W_SCAL + t] = 0; // redundant-safe (plain zero, pre-D2)
  u32 g = (b - 1) * 256u + t;
  if (g < 524288u) {                         // bad bitmap: zero + self-bit fused
    u32 row = g >> 7, cw = g & 127u;
    ws32[W_BAD + g] = (cw == (row >> 5)) ? (1u << (row & 31u)) : 0u;
  } else if (g < 525312u) {
    ws32[W_CCOUNT + (g - 524288u)] = 0u;     // chunk counts
  } else {                                   // out pad: nonzero fill_value=0 -> (src[0],dst[0])
    u32 r = g - 525312u;                     // r < 32768
    out[r] = (r < OUT_K) ? src[0] : dst[0];
  }
}

// --- D2: edge insert + dedup'd num_negatives + T9 publish (32 blocks) ---
// num_neg = E^2 - sum over distinct badset pairs (n,v) of cnt_src[n]*cnt_dst[v];
// self pairs handled by pre-set self-bits (k_init) + explicit self terms here.
__global__ void k_build(const int* __restrict__ src, const int* __restrict__ dst,
                        u32* __restrict__ ws32) {
  u32* bad     = ws32 + W_BAD;
  const u32* cs = ws32 + W_CNT_SRC;
  const u32* cd = ws32 + W_CNT_DST;
  u32* scal    = ws32 + W_SCAL;
  const u32 b = blockIdx.x, t = threadIdx.x;
  const u32 wv = t >> 6, ln = t & 63u;
  __shared__ u32 red[4];

  u32 e = b * 256u + t;                      // 32*256 = 8192 edges
  u32 s = (u32)src[e], d = (u32)dst[e];
  u32 bit = 1u << (d & 31u);
  u32 old = atomicOr(&bad[s * NBW + (d >> 5)], bit);
  u32 acc = (!(old & bit)) ? cs[s] * cd[d] : 0u;   // newly-set bit: exactly-once term
  if (t < 128u) {                            // self terms: 32 blocks x 128 = 4096
    u32 n = b * 128u + t;
    acc += cs[n] * cd[n];
  }
#pragma unroll
  for (int off = 32; off > 0; off >>= 1) acc += __shfl_down(acc, off, 64);
  if (ln == 0) red[wv] = acc;
  __syncthreads();
  if (t == 0) {
    atomicAdd(&scal[S_NEG], red[0] + red[1] + red[2] + red[3]);
    __threadfence();
    if (atomicAdd(&scal[S_TD], 1u) == 31u) { // last block publishes threshold
      u32 nn = TOT_N - atomicAdd(&scal[S_NEG], 0u);   // num_negatives
      u32 ratio = nn >> 13;                  // // E
      float kp = 2.0f / (float)ratio;        // f32(K)/f32(ratio), as JAX
      u32 T = (u32)ceil((double)kp * 8388608.0);      // u<kp <=> (bits>>9) < T
      u32 T9 = (T >= (1u << 23)) ? 0xFFFFFFFFu : (T << 9);
      atomicExch(&scal[S_T9], T9);
    }
  }
}

// --- D3: partitionable threefry, 8 elems/thread, 4-way interleaved chains ---
__global__ void __launch_bounds__(256, 8) k_sample(const int* __restrict__ src,
                                                   const int* __restrict__ dst,
                                                   const u32* __restrict__ ws32,
                                                   u64* __restrict__ keep_bm,
                                                   u32* __restrict__ ccount) {
  const u32* bad = ws32 + W_BAD;
  const u32 T9 = ws32[W_SCAL + S_T9];        // written in D2; dispatch boundary = visible
  const u32 wv = threadIdx.x >> 6, ln = threadIdx.x & 63u;
  const u32 i0w = blockIdx.x * 2048u + wv * 512u;  // wave covers 512 consecutive i
  u64 words[8]; u64 any = 0;
#pragma unroll
  for (int j = 0; j < 2; ++j) {
    u32 o[4];
    u32 ia = i0w + (u32)j * 256u + ln;
    threefry4_0_42(ia, ia + 64u, ia + 128u, ia + 192u, o);
#pragma unroll
    for (int m = 0; m < 4; ++m) {
      words[4 * j + m] = __ballot(o[m] < T9);
      any |= words[4 * j + m];
    }
  }
  if (any) {   // rare: refine kept lanes against bad bitmap
#pragma unroll
    for (int k = 0; k < 8; ++k) {
      if (words[k]) {
        u32 i = i0w + (u32)k * 64u + ln;
        bool kp2 = (words[k] >> ln) & 1ull;
        if (kp2) {
          u32 n = (u32)src[i >> 13], v = (u32)dst[i & 8191u];
          kp2 = ((bad[n * NBW + (v >> 5)] >> (v & 31u)) & 1u) == 0u;
        }
        words[k] = __ballot(kp2);
      }
    }
  }
  if (ln == 0) {
    ulonglong2* p = (ulonglong2*)&keep_bm[i0w >> 6];   // 64B aligned
    p[0] = make_ulonglong2(words[0], words[1]);
    p[1] = make_ulonglong2(words[2], words[3]);
    p[2] = make_ulonglong2(words[4], words[5]);
    p[3] = make_ulonglong2(words[6], words[7]);
    u32 c = 0;
#pragma unroll
    for (int k = 0; k < 8; ++k) c += (u32)__popcll(words[k]);
    if (c) atomicAdd(&ccount[i0w >> 16], c);
  }
}

// 64-lane inclusive scan via shfl
__device__ __forceinline__ u32 wave_iscan(u32 v, u32 ln) {
#pragma unroll
  for (int off = 1; off < 64; off <<= 1) {
    u32 n = __shfl_up(v, off, 64);
    if (ln >= (u32)off) v += n;
  }
  return v;
}

// --- D4: ordered compaction; inline scan of 1024 chunk counts (verified R7) ---
__global__ void k_compact(const int* __restrict__ src, const int* __restrict__ dst,
                          const u64* __restrict__ keep_bm, const u32* __restrict__ ccount,
                          int* __restrict__ out) {
  const u32 c = blockIdx.x, t = threadIdx.x;   // chunk c; 256 threads
  const u32 wv = t >> 6, ln = t & 63u;
  __shared__ u32 wtot[4], wtot2[4];
  __shared__ u32 base_sh;

  u32 v0 = ccount[4 * t], v1 = ccount[4 * t + 1], v2 = ccount[4 * t + 2], v3 = ccount[4 * t + 3];
  u32 s4 = v0 + v1 + v2 + v3;
  u32 is = wave_iscan(s4, ln);
  if (ln == 63) wtot[wv] = is;
  __syncthreads();
  u32 wpre = 0;
#pragma unroll
  for (int w = 0; w < 4; ++w) if ((u32)w < wv) wpre += wtot[w];
  if (t == (c >> 2)) {
    u32 excl = (is + wpre) - s4;
    if ((c & 3u) > 0) excl += v0;
    if ((c & 3u) > 1) excl += v1;
    if ((c & 3u) > 2) excl += v2;
    base_sh = excl;
  }
  __syncthreads();
  u32 rank0 = base_sh;

  const u64* wp = keep_bm + (size_t)c * 1024u;
  u64 w[4]; u32 cnt = 0;
#pragma unroll
  for (int k = 0; k < 4; ++k) { w[k] = wp[4 * t + k]; cnt += (u32)__popcll(w[k]); }
  u32 is2 = wave_iscan(cnt, ln);
  if (ln == 63) wtot2[wv] = is2;
  __syncthreads();
  u32 wpre2 = 0;
#pragma unroll
  for (int ww = 0; ww < 4; ++ww) if ((u32)ww < wv) wpre2 += wtot2[ww];
  u32 rank = rank0 + (is2 + wpre2) - cnt;
  u32 tb = (c << 16) + (t << 8);
#pragma unroll
  for (int k = 0; k < 4; ++k) {
    u64 bits = w[k];
    while (bits) {
      int bb = __ffsll((unsigned long long)bits) - 1;
      if (rank < OUT_K) {
        u32 tt = tb + (u32)k * 64u + (u32)bb;
        out[rank]         = src[tt >> 13];     // edge_src[rows]
        out[OUT_K + rank] = dst[tt & 8191u];   // edge_dst[cols]
      }
      rank++;
      bits &= bits - 1;
    }
  }
}

extern "C" void kernel_launch(void* const* d_in, const int* in_sizes, int n_in,
                              void* d_out, int out_size, void* d_ws, size_t ws_size,
                              hipStream_t stream) {
  const int* src = (const int*)d_in[1];  // edge_src
  const int* dst = (const int*)d_in[2];  // edge_dst  (node_feature d_in[0] unused)
  int* out = (int*)d_out;                // [edge_src_neg(16384) | edge_dst_neg(16384)]
  u32* ws32 = (u32*)d_ws;
  u64* keep_bm = (u64*)((char*)d_ws + OFF_KEEPBM);
  u32* ccount = ws32 + W_CCOUNT;

  k_init<<<2181, 256, 0, stream>>>(src, dst, ws32, out);
  k_build<<<32, 256, 0, stream>>>(src, dst, ws32);
  k_sample<<<TOT_N / 2048, 256, 0, stream>>>(src, dst, ws32, keep_bm, ccount);
  k_compact<<<1024, 256, 0, stream>>>(src, dst, keep_bm, ccount, out);
}

// Round 10
// 192.216 us; speedup vs baseline: 6.5303x; 1.0067x over previous
//
#include <hip/hip_runtime.h>
#include <stdint.h>
#include <math.h>

typedef unsigned int u32;
typedef unsigned long long u64;

#define E_CNT   8192
#define N_CNT   4096
#define TOT_N   67108864u      // E*E = 2^26
#define OUT_K   16384          // K*E
#define NBW     128            // bitmap words per node row

// ---- workspace word-offsets (u32 index into ws) ----
#define W_BAD      0           // u32[524288]  2 MiB bad bitmap
#define W_CCOUNT   532480      // u32[1024]
#define W_SCAL     533504      // u32[8]: [0]=neg_acc [1]=ticket [2]=T9
#define S_NEG 0
#define S_TD  1
#define S_T9  2
#define OFF_KEEPBM 0x210000    // bytes; u64[1<<20] 8 MiB (fully overwritten)

#define BLD_NB 128             // build blocks; each owns 32 node rows

// rotl as a single v_alignbit_b32
__device__ __forceinline__ u32 rotl32(u32 x, u32 d) {
  return __builtin_amdgcn_alignbit(x, x, 32u - d);
}

// Four interleaved JAX threefry2x32 evals, key=(0,42), counters (0,i0..i3).
// Returns bits = o0 ^ o1 per element (partitionable draw). Bit-exact (R2-R8: absmax 0).
__device__ __forceinline__ void threefry4_0_42(u32 i0, u32 i1, u32 i2, u32 i3, u32 o[4]) {
  const u32 k1 = 42u, k2 = 0x1BD11BF0u;   // 0 ^ 42 ^ 0x1BD11BDA
  u32 A0 = 0u, A1 = i0 + k1;
  u32 B0 = 0u, B1 = i1 + k1;
  u32 C0 = 0u, C1 = i2 + k1;
  u32 D0 = 0u, D1 = i3 + k1;
#define R4(r) { A0 += A1; B0 += B1; C0 += C1; D0 += D1; \
                A1 = rotl32(A1, r); B1 = rotl32(B1, r); C1 = rotl32(C1, r); D1 = rotl32(D1, r); \
                A1 ^= A0; B1 ^= B0; C1 ^= C0; D1 ^= D0; }
  R4(13) R4(15) R4(26) R4(6)
  A0 += k1; B0 += k1; C0 += k1; D0 += k1;
  A1 += k2 + 1u; B1 += k2 + 1u; C1 += k2 + 1u; D1 += k2 + 1u;
  R4(17) R4(29) R4(16) R4(24)
  A0 += k2; B0 += k2; C0 += k2; D0 += k2;
  A1 += 2u; B1 += 2u; C1 += 2u; D1 += 2u;
  R4(13) R4(15) R4(26) R4(6)
  A1 += k1 + 3u; B1 += k1 + 3u; C1 += k1 + 3u; D1 += k1 + 3u;
  R4(17) R4(29) R4(16) R4(24)
  A0 += k1; B0 += k1; C0 += k1; D0 += k1;
  A1 += k2 + 4u; B1 += k2 + 4u; C1 += k2 + 4u; D1 += k2 + 4u;
  R4(13) R4(15) R4(26) R4(6)
  A0 += k2; B0 += k2; C0 += k2; D0 += k2;
  A1 += 5u; B1 += 5u; C1 += 5u; D1 += 5u;
#undef R4
  o[0] = A0 ^ A1; o[1] = B0 ^ B1; o[2] = C0 ^ C1; o[3] = D0 ^ D1;
}

// --- D1 (after 8-B memset): self-contained build. Block b owns node rows [32b, 32b+32):
// LDS bitmap slice (zero+edges+self), redundant LDS histograms, per-row num_neg partial,
// FULL-slice store (4096 words = 16 uint4-stores/thread; R9 bug was storing only 1024),
// zero own ccount words, prefill own out slice, 128-ticket -> publish T9.
__global__ void __launch_bounds__(256) k_build(const int* __restrict__ src,
                                               const int* __restrict__ dst,
                                               u32* __restrict__ ws32,
                                               int* __restrict__ out) {
  __shared__ u32 bm[32 * NBW];   // 16 KB: my 32 rows
  __shared__ u32 hs[N_CNT];      // 16 KB: cnt_src (redundant per block)
  __shared__ u32 hd[N_CNT];      // 16 KB: cnt_dst
  __shared__ u32 red[4];
  u32* ccount = ws32 + W_CCOUNT;
  u32* scal   = ws32 + W_SCAL;
  const u32 b = blockIdx.x, t = threadIdx.x;
  const u32 wv = t >> 6, ln = t & 63u;
  const u32 rowlo = b * 32u;

#pragma unroll
  for (int k = 0; k < 16; ++k) {
    hs[t + 256 * k] = 0; hd[t + 256 * k] = 0; bm[t + 256 * k] = 0;
  }
  __syncthreads();
  // one pass over all edges: both histograms + insert edges hitting my rows
#pragma unroll
  for (int k = 0; k < 32; ++k) {
    u32 e = t + 256u * (u32)k;
    u32 s = (u32)src[e], d = (u32)dst[e];
    atomicAdd(&hs[s], 1u);
    atomicAdd(&hd[d], 1u);
    if ((s >> 5) == b) atomicOr(&bm[(s - rowlo) * NBW + (d >> 5)], 1u << (d & 31u));
  }
  if (t < 32u) {                 // self bit for row t (node rowlo+t)
    u32 n = rowlo + t;
    atomicOr(&bm[t * NBW + (n >> 5)], 1u << (n & 31u));
  }
  __syncthreads();

  // num_neg partial over my rows: one row per wave iteration
  u32 acc = 0;
  for (int r = (int)wv; r < 32; r += 4) {
    u32 n = rowlo + (u32)r;
    u32 sum = 0;
#pragma unroll
    for (int h = 0; h < 2; ++h) {
      u32 w = ln + 64u * (u32)h;
      u32 bits = bm[r * NBW + w];
      while (bits) { int bb = __ffs(bits) - 1; sum += hd[(w << 5) + (u32)bb]; bits &= bits - 1; }
    }
#pragma unroll
    for (int off = 32; off > 0; off >>= 1) sum += __shfl_down(sum, off, 64);
    if (ln == 0) acc += hs[n] * ((u32)E_CNT - sum);
  }
  if (ln == 0) red[wv] = acc;

  // write FULL bitmap slice: 4096 words, 16 words (4 uint4) per thread
  uint4* gslice = (uint4*)(ws32 + W_BAD + b * 4096u);
#pragma unroll
  for (int k = 0; k < 4; ++k) {
    u32 w0 = 1024u * (u32)k + 4u * t;
    gslice[256 * k + t] = make_uint4(bm[w0], bm[w0 + 1], bm[w0 + 2], bm[w0 + 3]);
  }
  if (t < 8u) ccount[b * 8u + t] = 0u;             // zero my chunk counters
  u32 oi = b * 256u + t;                           // out prefill: fill_value=0 -> (src[0],dst[0])
  out[oi] = (oi < OUT_K) ? src[0] : dst[0];

  __syncthreads();
  if (t == 0) {
    atomicAdd(&scal[S_NEG], red[0] + red[1] + red[2] + red[3]);
    __threadfence();
    if (atomicAdd(&scal[S_TD], 1u) == (u32)(BLD_NB - 1)) {   // last block publishes T9
      u32 nn = atomicAdd(&scal[S_NEG], 0u);        // num_negatives (direct sum)
      u32 ratio = nn >> 13;                        // // E
      float kp = 2.0f / (float)ratio;              // f32(K)/f32(ratio), as JAX
      u32 T = (u32)ceil((double)kp * 8388608.0);   // u<kp <=> (bits>>9) < T
      u32 T9 = (T >= (1u << 23)) ? 0xFFFFFFFFu : (T << 9);
      atomicExch(&scal[S_T9], T9);
    }
  }
}

// --- D2: partitionable threefry, 8 elems/thread (unchanged, verified 126 us floor) ---
__global__ void __launch_bounds__(256, 8) k_sample(const int* __restrict__ src,
                                                   const int* __restrict__ dst,
                                                   const u32* __restrict__ ws32,
                                                   u64* __restrict__ keep_bm,
                                                   u32* __restrict__ ccount) {
  const u32* bad = ws32 + W_BAD;
  const u32 T9 = ws32[W_SCAL + S_T9];        // written in D1; dispatch boundary = visible
  const u32 wv = threadIdx.x >> 6, ln = threadIdx.x & 63u;
  const u32 i0w = blockIdx.x * 2048u + wv * 512u;  // wave covers 512 consecutive i
  u64 words[8]; u64 any = 0;
#pragma unroll
  for (int j = 0; j < 2; ++j) {
    u32 o[4];
    u32 ia = i0w + (u32)j * 256u + ln;
    threefry4_0_42(ia, ia + 64u, ia + 128u, ia + 192u, o);
#pragma unroll
    for (int m = 0; m < 4; ++m) {
      words[4 * j + m] = __ballot(o[m] < T9);
      any |= words[4 * j + m];
    }
  }
  if (any) {   // rare: refine kept lanes against bad bitmap
#pragma unroll
    for (int k = 0; k < 8; ++k) {
      if (words[k]) {
        u32 i = i0w + (u32)k * 64u + ln;
        bool kp2 = (words[k] >> ln) & 1ull;
        if (kp2) {
          u32 n = (u32)src[i >> 13], v = (u32)dst[i & 8191u];
          kp2 = ((bad[n * NBW + (v >> 5)] >> (v & 31u)) & 1u) == 0u;
        }
        words[k] = __ballot(kp2);
      }
    }
  }
  if (ln == 0) {
    ulonglong2* p = (ulonglong2*)&keep_bm[i0w >> 6];   // 64B aligned
    p[0] = make_ulonglong2(words[0], words[1]);
    p[1] = make_ulonglong2(words[2], words[3]);
    p[2] = make_ulonglong2(words[4], words[5]);
    p[3] = make_ulonglong2(words[6], words[7]);
    u32 c = 0;
#pragma unroll
    for (int k = 0; k < 8; ++k) c += (u32)__popcll(words[k]);
    if (c) atomicAdd(&ccount[i0w >> 16], c);
  }
}

// 64-lane inclusive scan via shfl
__device__ __forceinline__ u32 wave_iscan(u32 v, u32 ln) {
#pragma unroll
  for (int off = 1; off < 64; off <<= 1) {
    u32 n = __shfl_up(v, off, 64);
    if (ln >= (u32)off) v += n;
  }
  return v;
}

// --- D3: ordered compaction; inline scan of 1024 chunk counts (verified R7/R8) ---
__global__ void k_compact(const int* __restrict__ src, const int* __restrict__ dst,
                          const u64* __restrict__ keep_bm, const u32* __restrict__ ccount,
                          int* __restrict__ out) {
  const u32 c = blockIdx.x, t = threadIdx.x;   // chunk c; 256 threads
  const u32 wv = t >> 6, ln = t & 63u;
  __shared__ u32 wtot[4], wtot2[4];
  __shared__ u32 base_sh;

  u32 v0 = ccount[4 * t], v1 = ccount[4 * t + 1], v2 = ccount[4 * t + 2], v3 = ccount[4 * t + 3];
  u32 s4 = v0 + v1 + v2 + v3;
  u32 is = wave_iscan(s4, ln);
  if (ln == 63) wtot[wv] = is;
  __syncthreads();
  u32 wpre = 0;
#pragma unroll
  for (int w = 0; w < 4; ++w) if ((u32)w < wv) wpre += wtot[w];
  if (t == (c >> 2)) {
    u32 excl = (is + wpre) - s4;
    if ((c & 3u) > 0) excl += v0;
    if ((c & 3u) > 1) excl += v1;
    if ((c & 3u) > 2) excl += v2;
    base_sh = excl;
  }
  __syncthreads();
  u32 rank0 = base_sh;

  const u64* wp = keep_bm + (size_t)c * 1024u;
  u64 w[4]; u32 cnt = 0;
#pragma unroll
  for (int k = 0; k < 4; ++k) { w[k] = wp[4 * t + k]; cnt += (u32)__popcll(w[k]); }
  u32 is2 = wave_iscan(cnt, ln);
  if (ln == 63) wtot2[wv] = is2;
  __syncthreads();
  u32 wpre2 = 0;
#pragma unroll
  for (int ww = 0; ww < 4; ++ww) if ((u32)ww < wv) wpre2 += wtot2[ww];
  u32 rank = rank0 + (is2 + wpre2) - cnt;
  u32 tb = (c << 16) + (t << 8);
#pragma unroll
  for (int k = 0; k < 4; ++k) {
    u64 bits = w[k];
    while (bits) {
      int bb = __ffsll((unsigned long long)bits) - 1;
      if (rank < OUT_K) {
        u32 tt = tb + (u32)k * 64u + (u32)bb;
        out[rank]         = src[tt >> 13];     // edge_src[rows]
        out[OUT_K + rank] = dst[tt & 8191u];   // edge_dst[cols]
      }
      rank++;
      bits &= bits - 1;
    }
  }
}

extern "C" void kernel_launch(void* const* d_in, const int* in_sizes, int n_in,
                              void* d_out, int out_size, void* d_ws, size_t ws_size,
                              hipStream_t stream) {
  const int* src = (const int*)d_in[1];  // edge_src
  const int* dst = (const int*)d_in[2];  // edge_dst  (node_feature d_in[0] unused)
  int* out = (int*)d_out;                // [edge_src_neg(16384) | edge_dst_neg(16384)]
  u32* ws32 = (u32*)d_ws;
  u64* keep_bm = (u64*)((char*)d_ws + OFF_KEEPBM);
  u32* ccount = ws32 + W_CCOUNT;

  hipMemsetAsync((char*)d_ws + (size_t)W_SCAL * 4, 0, 8, stream);  // neg_acc + ticket
  k_build<<<BLD_NB, 256, 0, stream>>>(src, dst, ws32, out);
  k_sample<<<TOT_N / 2048, 256, 0, stream>>>(src, dst, ws32, keep_bm, ccount);
  k_compact<<<1024, 256, 0, stream>>>(src, dst, keep_bm, ccount, out);
}